// Round 10
// baseline (368.942 us; speedup 1.0000x reference)
//
#include <hip/hip_runtime.h>
#include <math.h>

// Problem dims (fixed by setup_inputs)
constexpr int B  = 16;
constexpr int H  = 32;
constexpr int S  = 2048;
constexpr int DK = 128;
constexpr int D  = 4096;   // H*DK
constexpr int BH = B * H;  // 512

constexpr int NSPLIT = 4;          // S-splits per (b,h)
constexpr int CHUNK  = S / NSPLIT; // 512
constexpr int NREC   = NSPLIT * 4; // 16 partial records per bh
constexpr int REC    = 132;        // floats per record: acc[128], l, pad3

// ---------------------------------------------------------------------------
// Merging butterflies. reduce64: lane L ends with full-wave total of v[L].
// reduce16: lane L ends with full-wave total of v[L & 15] (4 xor stages over
// 16-lane groups + cross-adds at 16 and 32) — same verified pattern family
// as reduce32 (R5, end-to-end checked).
// ---------------------------------------------------------------------------
__device__ __forceinline__ float reduce64(float v[64], int lane) {
    #pragma unroll
    for (int s = 0; s < 6; ++s) {
        const int off = 1 << s;
        #pragma unroll
        for (int j = 0; j < (64 >> (s + 1)); ++j) {
            const float lo = v[2 * j], hi = v[2 * j + 1];
            const bool  up = (lane & off) != 0;
            const float mine = up ? hi : lo;
            const float oth  = up ? lo : hi;
            v[j] = mine + __shfl_xor(oth, off, 64);
        }
    }
    return v[0];
}

__device__ __forceinline__ float reduce16(float v[16], int lane) {
    #pragma unroll
    for (int s = 0; s < 4; ++s) {
        const int off = 1 << s;
        #pragma unroll
        for (int j = 0; j < (16 >> (s + 1)); ++j) {
            const float lo = v[2 * j], hi = v[2 * j + 1];
            const bool  up = (lane & off) != 0;
            const float mine = up ? hi : lo;
            const float oth  = up ? lo : hi;
            v[j] = mine + __shfl_xor(oth, off, 64);
        }
    }
    float t = v[0];
    t += __shfl_xor(t, 16, 64);
    t += __shfl_xor(t, 32, 64);
    return t;
}

// ---------------------------------------------------------------------------
// Q projection (R4 proj body, frozen). Only Wq: grid 4096/16 = 256 blocks.
// ---------------------------------------------------------------------------
__global__ __launch_bounds__(256, 3) void proj_q_kernel(
    const float* __restrict__ X,
    const float* __restrict__ Wq,
    float* __restrict__ Yq)
{
    __shared__ float4 xs[2][16][64];   // [buf][batch][k-float4] = 2 x 16 KB

    const int t    = threadIdx.x;
    const int lane = t & 63;
    const int wid  = t >> 6;
    const int tb   = t >> 4;
    const int tf   = t & 15;

    const int n0 = blockIdx.x * 16 + wid * 4;    // 4 cols per wave

    const float4* w4 = (const float4*)Wq;
    const float4* x4 = (const float4*)X;          // [16][1024]

    float acc[64];
    #pragma unroll
    for (int i = 0; i < 64; ++i) acc[i] = 0.f;

    float4 xr[4];
    #pragma unroll
    for (int i = 0; i < 4; ++i) xr[i] = x4[tb * 1024 + tf + 16 * i];
    float4 wv[4];
    #pragma unroll
    for (int c = 0; c < 4; ++c) wv[c] = w4[(size_t)(n0 + c) * 1024 + lane];
    #pragma unroll
    for (int i = 0; i < 4; ++i) xs[0][tb][tf + 16 * i] = xr[i];
    __syncthreads();

    for (int ch = 0; ch < 16; ++ch) {
        float4 xn[4], wn[4];
        const bool more = (ch < 15);
        if (more) {
            #pragma unroll
            for (int i = 0; i < 4; ++i)
                xn[i] = x4[tb * 1024 + (ch + 1) * 64 + tf + 16 * i];
            #pragma unroll
            for (int c = 0; c < 4; ++c)
                wn[c] = w4[(size_t)(n0 + c) * 1024 + (ch + 1) * 64 + lane];
        }
        const int buf = ch & 1;
        #pragma unroll
        for (int b = 0; b < 16; ++b) {
            const float4 xv = xs[buf][b][lane];
            #pragma unroll
            for (int c = 0; c < 4; ++c)
                acc[b * 4 + c] += xv.x * wv[c].x + xv.y * wv[c].y +
                                  xv.z * wv[c].z + xv.w * wv[c].w;
        }
        if (more) {
            #pragma unroll
            for (int i = 0; i < 4; ++i) xs[buf ^ 1][tb][tf + 16 * i] = xn[i];
            __syncthreads();
            #pragma unroll
            for (int c = 0; c < 4; ++c) wv[c] = wn[c];
        }
    }

    const float outv = reduce64(acc, lane);
    Yq[(size_t)(lane >> 2) * D + n0 + (lane & 3)] = outv;
}

// ---------------------------------------------------------------------------
// FUSED attention + KV projection. Grid = BH*NSPLIT = 2048 blocks, 256 thr,
// no LDS -> all blocks co-resident (8 blocks/CU, 32 waves/CU).
// Phase 1 (per wave): R4 flash-decode over positions [s0, min(s0+512, sp))
//   -- position sp EXCLUDED, so the hot loop has no k_new/v_new select.
// Phase 2 (per wave): ONE column of the K/V projection (col = bid*4+wid;
//   cols 0..4095 -> Wk/k_new, 4096..8191 -> Wv/v_new). W streams from HBM
//   hidden under the BW-bound attention window; x served from L1/L2.
// ---------------------------------------------------------------------------
__global__ __launch_bounds__(256) void attn_kvproj_kernel(
    const float* __restrict__ q,        // [BH][DK]
    const float* __restrict__ k_cache,  // [B][H][S][DK]
    const float* __restrict__ v_cache,
    const float* __restrict__ X,        // [16][4096]
    const float* __restrict__ Wk,
    const float* __restrict__ Wv,
    const int*   __restrict__ start_pos_p,
    float* __restrict__ part,           // [BH][NREC][REC]
    float* __restrict__ k_new,          // [B][D] as [bh][DK]
    float* __restrict__ v_new)
{
    const int lane  = threadIdx.x & 63;
    const int wid   = threadIdx.x >> 6;
    const int half  = lane >> 5;
    const int hl    = lane & 31;
    const int bh    = blockIdx.x & (BH - 1);
    const int split = blockIdx.x >> 9;

    const int sp    = start_pos_p[0];
    const int s0    = split * CHUNK;
    const int s_end = (s0 + CHUNK < sp) ? (s0 + CHUNK) : sp;  // excludes sp

    // ---- Phase 1: attention over old positions (R4 pattern, frozen) ----
    const float qscale = 0.08838834764831845f * 1.4426950408889634f;
    const float shift  = 8.0f * 1.4426950408889634f;
    float4 qv = *(const float4*)(q + (size_t)bh * DK + 4 * hl);
    qv.x *= qscale; qv.y *= qscale; qv.z *= qscale; qv.w *= qscale;

    const float* kbase = k_cache + (size_t)bh * S * DK;
    const float* vbase = v_cache + (size_t)bh * S * DK;

    float  l = 0.f;
    float4 acc = make_float4(0.f, 0.f, 0.f, 0.f);

    #pragma unroll 4
    for (int s2 = s0 + 2 * wid; s2 < s_end; s2 += 8) {
        const int  pos   = s2 + half;
        const bool valid = pos < s_end;
        const int  cpos  = valid ? pos : (s_end - 1);
        const float4 kv = *(const float4*)(kbase + (size_t)cpos * DK + 4 * hl);
        const float4 vv = *(const float4*)(vbase + (size_t)cpos * DK + 4 * hl);

        float p = kv.x * qv.x + kv.y * qv.y + kv.z * qv.z + kv.w * qv.w;
        p += __shfl_xor(p, 1, 64);
        p += __shfl_xor(p, 2, 64);
        p += __shfl_xor(p, 4, 64);
        p += __shfl_xor(p, 8, 64);
        p += __shfl_xor(p, 16, 64);

        const float ep = valid ? __builtin_amdgcn_exp2f(p - shift) : 0.f;
        l     += ep;
        acc.x += ep * vv.x;
        acc.y += ep * vv.y;
        acc.z += ep * vv.z;
        acc.w += ep * vv.w;
    }

    l     += __shfl_xor(l, 32, 64);
    acc.x += __shfl_xor(acc.x, 32, 64);
    acc.y += __shfl_xor(acc.y, 32, 64);
    acc.z += __shfl_xor(acc.z, 32, 64);
    acc.w += __shfl_xor(acc.w, 32, 64);

    float* rec = part + ((size_t)bh * NREC + split * 4 + wid) * REC;
    if (half == 0) *(float4*)(rec + 4 * hl) = acc;
    if (lane == 0) rec[128] = l;

    // ---- Phase 2: one K/V projection column per wave ----
    const int col = blockIdx.x * 4 + wid;          // 0..8191
    const int n   = col & (D - 1);
    const float* Wp = (col < D) ? Wk : Wv;
    float*       Yp = (col < D) ? k_new : v_new;
    const float4* w4 = (const float4*)(Wp + (size_t)n * D);
    const float4* x4 = (const float4*)X;           // [16][1024]

    float pacc[16];
    #pragma unroll
    for (int i = 0; i < 16; ++i) pacc[i] = 0.f;

    float4 wrow = w4[lane];
    for (int ch = 0; ch < 16; ++ch) {
        float4 wnext;
        if (ch < 15) wnext = w4[(ch + 1) * 64 + lane];
        #pragma unroll
        for (int b = 0; b < 16; ++b) {
            const float4 xv = x4[b * 1024 + ch * 64 + lane];
            pacc[b] += xv.x * wrow.x + xv.y * wrow.y +
                       xv.z * wrow.z + xv.w * wrow.w;
        }
        if (ch < 15) wrow = wnext;
    }

    const float tot = reduce16(pacc, lane);
    if (lane < 16)
        Yp[(size_t)lane * D + n] = tot;
}

// ---------------------------------------------------------------------------
// Combine: sum NREC partials (shared fixed shift) + the last position's
// contribution computed analytically from q, k_new, v_new. Grid = BH x 64.
// ---------------------------------------------------------------------------
__global__ __launch_bounds__(64) void combine_kernel(
    const float* __restrict__ part,
    const float* __restrict__ q,
    const float* __restrict__ k_new,
    const float* __restrict__ v_new,
    float* __restrict__ attn_out)       // [B][D] laid out as [bh][DK]
{
    const int bh   = blockIdx.x;
    const int lane = threadIdx.x;
    const float* base = part + (size_t)bh * NREC * REC;

    float L = 0.f, o0 = 0.f, o1 = 0.f;
    #pragma unroll
    for (int i = 0; i < NREC; ++i) {
        L += base[i * REC + 128];
        const float2 a = *(const float2*)(base + i * REC + 2 * lane);
        o0 += a.x;
        o1 += a.y;
    }

    // Last position (s == start_pos): score = q . k_new / sqrt(128)
    const float qscale = 0.08838834764831845f * 1.4426950408889634f;
    const float shift  = 8.0f * 1.4426950408889634f;
    const float2 q2 = *(const float2*)(q     + (size_t)bh * DK + 2 * lane);
    const float2 kn = *(const float2*)(k_new + (size_t)bh * DK + 2 * lane);
    const float2 vn = *(const float2*)(v_new + (size_t)bh * DK + 2 * lane);

    float p = q2.x * kn.x + q2.y * kn.y;
    p += __shfl_xor(p, 1, 64);
    p += __shfl_xor(p, 2, 64);
    p += __shfl_xor(p, 4, 64);
    p += __shfl_xor(p, 8, 64);
    p += __shfl_xor(p, 16, 64);
    p += __shfl_xor(p, 32, 64);

    const float ep = __builtin_amdgcn_exp2f(p * qscale - shift);
    L  += ep;
    o0 += ep * vn.x;
    o1 += ep * vn.y;

    const float inv = 1.f / L;
    attn_out[(size_t)bh * DK + 2 * lane]     = o0 * inv;
    attn_out[(size_t)bh * DK + 2 * lane + 1] = o1 * inv;
}

// ---------------------------------------------------------------------------
// Wo projection (R4 design, frozen). 4 columns per block, K-dim split across
// the 4 waves, merged via LDS. Grid = D/4 = 1024 blocks.
// ---------------------------------------------------------------------------
__global__ __launch_bounds__(256) void proj_wo_kernel(
    const float* __restrict__ X,
    const float* __restrict__ Wo,
    float* __restrict__ out)
{
    __shared__ float red[4][64];
    const int lane = threadIdx.x & 63;
    const int wid  = threadIdx.x >> 6;
    const int n0   = blockIdx.x * 4;
    const float4* w4 = (const float4*)Wo;
    const float4* x4 = (const float4*)X;

    float acc[64];
    #pragma unroll
    for (int i = 0; i < 64; ++i) acc[i] = 0.f;

    #pragma unroll
    for (int it = 0; it < 4; ++it) {
        const int d4 = wid * 256 + it * 64 + lane;
        float4 wv[4];
        #pragma unroll
        for (int c = 0; c < 4; ++c) wv[c] = w4[(size_t)(n0 + c) * 1024 + d4];
        #pragma unroll
        for (int b = 0; b < 16; ++b) {
            const float4 xv = x4[b * 1024 + d4];
            #pragma unroll
            for (int c = 0; c < 4; ++c)
                acc[b * 4 + c] += xv.x * wv[c].x + xv.y * wv[c].y +
                                  xv.z * wv[c].z + xv.w * wv[c].w;
        }
    }

    const float pv = reduce64(acc, lane);
    red[wid][lane] = pv;
    __syncthreads();
    if (wid == 0) {
        const float tot = red[0][lane] + red[1][lane] + red[2][lane] + red[3][lane];
        out[(size_t)(lane >> 2) * D + n0 + (lane & 3)] = tot;
    }
}

// ---------------------------------------------------------------------------
extern "C" void kernel_launch(void* const* d_in, const int* in_sizes, int n_in,
                              void* d_out, int out_size, void* d_ws, size_t ws_size,
                              hipStream_t stream)
{
    const float* x       = (const float*)d_in[0];
    const float* k_cache = (const float*)d_in[1];
    const float* v_cache = (const float*)d_in[2];
    const float* Wq      = (const float*)d_in[3];
    const float* Wk      = (const float*)d_in[4];
    const float* Wv      = (const float*)d_in[5];
    const float* Wo      = (const float*)d_in[6];
    const int*   sp      = (const int*)d_in[7];
    float*       out     = (float*)d_out;

    float* ws       = (float*)d_ws;
    float* q        = ws;                    // B*D = 65536 floats
    float* k_new    = ws + 65536;
    float* v_new    = ws + 131072;
    float* attn_out = ws + 196608;
    float* part     = ws + 262144;           // BH*NREC*REC floats

    // Q projection only (attention's sole dependency)
    proj_q_kernel<<<D / 16, 256, 0, stream>>>(x, Wq, q);

    // Fused: flash-decode over old positions + K/V projection riding along
    attn_kvproj_kernel<<<BH * NSPLIT, 256, 0, stream>>>(
        q, k_cache, v_cache, x, Wk, Wv, sp, part, k_new, v_new);

    // Merge partials + analytic last-position term
    combine_kernel<<<BH, 64, 0, stream>>>(part, q, k_new, v_new, attn_out);

    // Output projection
    proj_wo_kernel<<<D / 4, 256, 0, stream>>>(attn_out, Wo, out);
}